// Round 18
// baseline (44.100 us; speedup 1.0000x reference)
//
#include <hip/hip_runtime.h>
#include <hip/hip_bf16.h>
#include <math.h>

#define BATCH 512
#define NC 100

typedef __attribute__((ext_vector_type(8))) short bf16x8;
typedef __attribute__((ext_vector_type(4))) float f32x4;

__device__ inline ushort f2bf(float f) {
    __hip_bfloat16 h = __float2bfloat16(f);
    return *reinterpret_cast<ushort*>(&h);
}

// ---------------- cvt: fc w f32->bf16 (0..1599), conv2 w transpose (1600..1887), conv1 im2col w (1888..1903) ----------------
__global__ __launch_bounds__(256) void cvt_all_kernel(const float* __restrict__ fw,
                                                      ushort* __restrict__ fwb,
                                                      const float* __restrict__ w2,
                                                      ushort* __restrict__ w2t,
                                                      const float* __restrict__ w1,
                                                      ushort* __restrict__ w1t)
{
    const int blk = blockIdx.x;
    if (blk < 1600) {
        const int i = (blk * 256 + threadIdx.x) * 4;   // 1,638,400 exact
        float4 v = *(const float4*)(fw + i);
        ushort o[4];
        o[0] = f2bf(v.x); o[1] = f2bf(v.y); o[2] = f2bf(v.z); o[3] = f2bf(v.w);
        *(uint2*)(fwb + i) = *(uint2*)o;
    } else if (blk < 1888) {
        const int i = (blk - 1600) * 256 + threadIdx.x;  // 73,728 exact
        const int ic = i & 31;
        const int oc = (i >> 5) & 63;
        const int et = i >> 11;
        const int e = et / 9, t = et % 9;
        w2t[i] = f2bf(w2[((e * 64 + oc) * 32 + ic) * 9 + t]);
    } else {
        // w1t[4][32oc][32k] bf16, k = ic*9+tap (27 real, 5 zero-pad)
        const int i = (blk - 1888) * 256 + threadIdx.x;  // 4096 exact
        const int row = i >> 5, k = i & 31;              // row = e*32+oc
        w1t[i] = (k < 27) ? f2bf(w1[row * 27 + k]) : (ushort)0;
    }
}

// ---------------- fused per-sample, 512 threads (8 waves): router(fp32) -> top1 -> conv1(MFMA) -> conv2(MFMA) ----------------
__global__ __launch_bounds__(512) void fused_expert_kernel(
    const float* __restrict__ x,       // [B,3,32,32]
    const float* __restrict__ rcw,     // [16,3,3,3]
    const float* __restrict__ rcb,     // [16]
    const float* __restrict__ rfw,     // [4,16]
    const float* __restrict__ rfb,     // [4]
    const ushort* __restrict__ w1t,    // [4][32][32] bf16 im2col conv1 weights (L2)
    const float* __restrict__ eb1,     // [4,32]
    const ushort* __restrict__ w2t,    // [4][9][64][32] bf16 (L2)
    const float* __restrict__ eb2,     // [4,64]
    float* __restrict__ probs_out,     // [512,4]
    int* __restrict__ sel,             // [512]
    float* __restrict__ pw,            // [512]
    uint* __restrict__ h2b)            // [B][2048] u32 (bf16 pairs): oc*64+py*8+px
{
    __shared__ float xs[3 * 34 * 40];                    // rows padded to 40 floats, 16.3 KB
    __shared__ float rcb_s[16];
    __shared__ float rfw_s[68];                          // [4][16] + 4 bias
    __shared__ float red[8][16];
    __shared__ float g_s[16];
    __shared__ int   sel_s;
    __shared__ float eb1_s[128];
    __shared__ __align__(16) ushort A_s[18 * 18 * 32];   // conv2 input, halo-padded, 20.7 KB

    const int b = blockIdx.x, tid = threadIdx.x;
    const int wvv = tid >> 6, lane = tid & 63;
    const int lr = lane & 15, kb = lane >> 4;

    // ---- phase 0: zero A_s halo + xs, stage small tables, then xs interior ----
    uint* A32 = (uint*)A_s;
    for (int i = tid; i < 1088; i += 512) {
        int y, xx, w;
        if (i < 576) { y = (i >= 288) ? 17 : 0; int r2 = i % 288; xx = r2 >> 4; w = r2 & 15; }
        else { int j = i - 576; y = 1 + (j >> 5); xx = ((j >> 4) & 1) ? 17 : 0; w = j & 15; }
        A32[(y * 18 + xx) * 16 + w] = 0u;
    }
    for (int i = tid; i < 3 * 34 * 40; i += 512) xs[i] = 0.f;
    if (tid < 128) eb1_s[tid] = eb1[tid];
    if (tid < 68) rfw_s[tid] = (tid < 64) ? rfw[tid] : rfb[tid - 64];
    if (tid >= 128 && tid < 144) rcb_s[tid - 128] = rcb[tid - 128];
    __syncthreads();
    const float* xb = x + b * 3072;
    for (int i = tid; i < 3072; i += 512) {
        int c = i >> 10, r = (i >> 5) & 31, cc = i & 31;
        xs[(c * 34 + r + 1) * 40 + (cc + 1)] = xb[i];
    }
    __syncthreads();

    // ---- phase 1: router conv+relu+mean fp32; thread = (oc 0..15) x (pg 0..15, half 0..1) ----
    {
        const int oc = tid & 15, sg = tid >> 4;      // sg 0..31
        const int pg = sg & 15, half = sg >> 4;
        const int c0 = half * 16;
        float w[27];
#pragma unroll
        for (int j = 0; j < 27; ++j) w[j] = rcw[oc * 27 + j];
        const float bias = rcb_s[oc];
        float a0[16], a1[16];
#pragma unroll
        for (int j = 0; j < 16; ++j) { a0[j] = 0.f; a1[j] = 0.f; }
#pragma unroll
        for (int c = 0; c < 3; ++c) {
#pragma unroll
            for (int ry = 0; ry < 4; ++ry) {
                const float* row = &xs[(c * 34 + 2 * pg + ry) * 40 + c0];
                float rv[18];
                float4 q0 = *(const float4*)(row);
                float4 q1 = *(const float4*)(row + 4);
                float4 q2 = *(const float4*)(row + 8);
                float4 q3 = *(const float4*)(row + 12);
                float2 q4 = *(const float2*)(row + 16);
                rv[0] = q0.x; rv[1] = q0.y; rv[2] = q0.z; rv[3] = q0.w;
                rv[4] = q1.x; rv[5] = q1.y; rv[6] = q1.z; rv[7] = q1.w;
                rv[8] = q2.x; rv[9] = q2.y; rv[10] = q2.z; rv[11] = q2.w;
                rv[12] = q3.x; rv[13] = q3.y; rv[14] = q3.z; rv[15] = q3.w;
                rv[16] = q4.x; rv[17] = q4.y;
                if (ry < 3) {
#pragma unroll
                    for (int kx = 0; kx < 3; ++kx) {
                        const float wv = w[c * 9 + ry * 3 + kx];
#pragma unroll
                        for (int j = 0; j < 16; ++j) a0[j] += wv * rv[j + kx];
                    }
                }
                if (ry > 0) {
#pragma unroll
                    for (int kx = 0; kx < 3; ++kx) {
                        const float wv = w[c * 9 + (ry - 1) * 3 + kx];
#pragma unroll
                        for (int j = 0; j < 16; ++j) a1[j] += wv * rv[j + kx];
                    }
                }
            }
        }
        float accm = 0.f;
#pragma unroll
        for (int j = 0; j < 16; ++j)
            accm += fmaxf(a0[j] + bias, 0.f) + fmaxf(a1[j] + bias, 0.f);
        // wave holds 4 sg x 16 oc: lane = ((sg&3)<<4)|oc
        accm += __shfl_down(accm, 32);
        accm += __shfl_down(accm, 16);
        if (lane < 16) red[wvv][lane] = accm;   // lane<16 -> oc = lane
    }
    __syncthreads();
    if (tid < 16) {
        float s = 0.f;
#pragma unroll
        for (int w = 0; w < 8; ++w) s += red[w][tid];
        g_s[tid] = s * (1.f / 1024.f);
    }
    __syncthreads();

    // ---- phase 2: fc(16->4) + softmax + top1 (thread 0, all-LDS) ----
    if (tid == 0) {
        float logits[4];
#pragma unroll
        for (int e = 0; e < 4; ++e) {
            float s = rfw_s[64 + e];
#pragma unroll
            for (int o = 0; o < 16; ++o) s += g_s[o] * rfw_s[e * 16 + o];
            logits[e] = s;
        }
        float m = fmaxf(fmaxf(logits[0], logits[1]), fmaxf(logits[2], logits[3]));
        float ex[4], ssum = 0.f;
#pragma unroll
        for (int e = 0; e < 4; ++e) { ex[e] = __expf(logits[e] - m); ssum += ex[e]; }
        const float inv = 1.f / ssum;
        float p[4];
#pragma unroll
        for (int e = 0; e < 4; ++e) p[e] = ex[e] * inv;
        int am = 0; float best = p[0];
#pragma unroll
        for (int e = 1; e < 4; ++e) { if (p[e] > best) { best = p[e]; am = e; } }
        *(float4*)(probs_out + b * 4) = make_float4(p[0], p[1], p[2], p[3]);
        sel[b] = am;
        pw[b] = best;
        sel_s = am;
    }
    __syncthreads();
    const int e = sel_s;

    // ---- phase 4: conv1 via im2col MFMA; 8 waves x 8 mf (M=1024 corner-major, N=32, K=32) ----
    {
        const ushort* bsrc = w1t + (e * 32 + lr) * 32 + kb * 8;   // L2-hot 8 KB table
        const bf16x8 b0 = *(const bf16x8*)(bsrc);
        const bf16x8 b1 = *(const bf16x8*)(bsrc + 16 * 32);
        const float bv0 = eb1_s[e * 32 + lr];
        const float bv1 = eb1_s[e * 32 + 16 + lr];

        int offj[8], valj[8];
#pragma unroll
        for (int jj = 0; jj < 8; ++jj) {
            int k = kb * 8 + jj;
            int ic = (k * 57) >> 9; ic = ic > 2 ? 2 : ic;
            int tap = k - ic * 9; tap = tap > 8 ? 8 : tap;
            int ky = (tap * 11) >> 5;
            int kx = tap - ky * 3;
            offj[jj] = (ic * 34 + ky) * 40 + kx;
            valj[jj] = (k < 27);
        }

#pragma unroll 2
        for (int mf = 0; mf < 8; ++mf) {
            const int pA = wvv * 32 + mf * 4 + (lr >> 2);  // pooled pixel of this im2col row
            const int c2 = lr & 3;                         // corner
            const int yA = ((pA >> 4) << 1) + (c2 >> 1);
            const int xA = ((pA & 15) << 1) + (c2 & 1);
            const int base = yA * 40 + xA;
            union { uint u[4]; bf16x8 v; } U;
#pragma unroll
            for (int jp = 0; jp < 4; ++jp) {
                float v0 = valj[2 * jp]     ? xs[base + offj[2 * jp]]     : 0.f;
                float v1 = valj[2 * jp + 1] ? xs[base + offj[2 * jp + 1]] : 0.f;
                U.u[jp] = (uint)f2bf(v0) | ((uint)f2bf(v1) << 16);
            }
            const f32x4 z = {0.f, 0.f, 0.f, 0.f};
            f32x4 c0 = __builtin_amdgcn_mfma_f32_16x16x32_bf16(U.v, b0, z, 0, 0, 0);
            f32x4 c1 = __builtin_amdgcn_mfma_f32_16x16x32_bf16(U.v, b1, z, 0, 0, 0);
            const int pp = wvv * 32 + mf * 4 + kb;
            const int py = pp >> 4, px = pp & 15;
            ushort* dst = A_s + ((py + 1) * 18 + (px + 1)) * 32 + lr;
            float m0 = fmaxf(fmaxf(c0[0], c0[1]), fmaxf(c0[2], c0[3]));
            float m1 = fmaxf(fmaxf(c1[0], c1[1]), fmaxf(c1[2], c1[3]));
            dst[0]  = f2bf(fmaxf(m0 + bv0, 0.f));
            dst[16] = f2bf(fmaxf(m1 + bv1, 0.f));
        }
    }
    __syncthreads();

    // ---- phase 5: conv2 via 9 tap-MFMAs; 8 waves = (wy 0..3) x (wn 0..1), acc[4][2] ----
    {
        const int wy = wvv & 3, wn = wvv >> 2;
        const ushort* wgl = w2t + (size_t)e * 18432 + lr * 32 + kb * 8;

        f32x4 acc[4][2];
#pragma unroll
        for (int m = 0; m < 4; ++m)
#pragma unroll
            for (int n = 0; n < 2; ++n)
                acc[m][n] = (f32x4){0.f, 0.f, 0.f, 0.f};

#pragma unroll
        for (int t = 0; t < 9; ++t) {
            const int ky = t / 3, kx = t % 3;
            bf16x8 af[4], bfr[2];
#pragma unroll
            for (int m = 0; m < 4; ++m) {
                const int y = wy * 4 + m;
                af[m] = *(const bf16x8*)(A_s + ((y + ky) * 18 + (lr + kx)) * 32 + kb * 8);
            }
#pragma unroll
            for (int n = 0; n < 2; ++n)
                bfr[n] = *(const bf16x8*)(wgl + (t * 64 + (wn * 2 + n) * 16) * 32);
#pragma unroll
            for (int m = 0; m < 4; ++m)
#pragma unroll
                for (int n = 0; n < 2; ++n)
                    acc[m][n] = __builtin_amdgcn_mfma_f32_16x16x32_bf16(af[m], bfr[n], acc[m][n], 0, 0, 0);
        }

#pragma unroll
        for (int q = 0; q < 2; ++q) {
            const int py = wy * 2 + q;
#pragma unroll
            for (int n = 0; n < 2; ++n) {
                const int oc = (wn * 2 + n) * 16 + lr;
                const float bn = eb2[e * 64 + oc];
                const f32x4 ca = acc[2 * q][n];
                const f32x4 cb = acc[2 * q + 1][n];
                float p0 = fmaxf(fmaxf(ca[0], ca[1]), fmaxf(cb[0], cb[1]));
                float p1 = fmaxf(fmaxf(ca[2], ca[3]), fmaxf(cb[2], cb[3]));
                float r0 = fmaxf(p0 + bn, 0.f);
                float r1 = fmaxf(p1 + bn, 0.f);
                uint pk = (uint)f2bf(r0) | ((uint)f2bf(r1) << 16);
                h2b[(size_t)b * 2048 + oc * 32 + py * 4 + kb] = pk;
            }
        }
    }
}

// ---------------- fc: per-block ballot grouping + K-split MFMA, M-tile 32 (2 m-frags/wave) ----------------
// grid (mt 0..15, ks 0..7, e 0..3); block 448 = 7 waves; halved B re-reads vs M=16.
__global__ __launch_bounds__(448) void fc_mfma_kernel(
    const ushort* __restrict__ h2b,   // [512,4096] bf16
    const ushort* __restrict__ fwb,   // [4,100,4096] bf16
    const int* __restrict__ sel,      // [512]
    float* __restrict__ part)         // [8][512][100] f32
{
    __shared__ int wcnt[4][8];
    __shared__ int wbase[4][8];
    __shared__ int soff[5];
    __shared__ int sids[512];

    const int mt = blockIdx.x, ks = blockIdx.y, e = blockIdx.z;
    const int tid = threadIdx.x;
    const int wv = tid >> 6, lane = tid & 63;

    // ---- grouping preamble ----
    const int s0 = wv * 64 + lane;          // 0..447
    const int e0 = sel[s0];
    unsigned long long m0[4];
#pragma unroll
    for (int k = 0; k < 4; ++k) m0[k] = __ballot(e0 == k);
    if (lane == 0) {
#pragma unroll
        for (int k = 0; k < 4; ++k) wcnt[k][wv] = __popcll(m0[k]);
    }
    int e1 = 0;
    unsigned long long m1[4] = {0, 0, 0, 0};
    if (wv == 0) {
        const int s1 = 448 + lane;
        e1 = sel[s1];
#pragma unroll
        for (int k = 0; k < 4; ++k) m1[k] = __ballot(e1 == k);
        if (lane == 0) {
#pragma unroll
            for (int k = 0; k < 4; ++k) wcnt[k][7] = __popcll(m1[k]);
        }
    }
    __syncthreads();
    if (tid == 0) {
        int o = 0;
        for (int k = 0; k < 4; ++k) {
            soff[k] = o;
            for (int w = 0; w < 8; ++w) { wbase[k][w] = o; o += wcnt[k][w]; }
        }
        soff[4] = o;
    }
    __syncthreads();
    const unsigned long long below = (lane == 0) ? 0ull : (~0ull >> (64 - lane));
    {
        const int r = __popcll(m0[e0] & below);
        sids[wbase[e0][wv] + r] = s0;
    }
    if (wv == 0) {
        const int r = __popcll(m1[e1] & below);
        sids[wbase[e1][7] + r] = 448 + lane;
    }
    __syncthreads();

    const int off = soff[e], cnt = soff[e + 1] - off;
    if (mt * 32 >= cnt) return;

    // ---- MFMA K-split GEMM, two m-fragments per wave ----
    const int lr = lane & 15, kb = lane >> 4;
    const int cls = wv * 16 + lr;
    const int clsc = cls < NC ? cls : NC - 1;
    const int slot0 = mt * 32 + lr;
    const int slot1 = slot0 + 16;
    const int sidx0 = sids[off + (slot0 < cnt ? slot0 : cnt - 1)];
    const int sidx1 = sids[off + (slot1 < cnt ? slot1 : cnt - 1)];

    const ushort* ap0 = h2b + (size_t)sidx0 * 4096 + ks * 512 + kb * 8;
    const ushort* ap1 = h2b + (size_t)sidx1 * 4096 + ks * 512 + kb * 8;
    const ushort* bp  = fwb + (size_t)(e * NC + clsc) * 4096 + ks * 512 + kb * 8;

    f32x4 acc0 = {0.f, 0.f, 0.f, 0.f};
    f32x4 acc1 = {0.f, 0.f, 0.f, 0.f};
#pragma unroll
    for (int k = 0; k < 16; ++k) {
        bf16x8 bvv = *(const bf16x8*)(bp + k * 32);
        bf16x8 a0 = *(const bf16x8*)(ap0 + k * 32);
        bf16x8 a1 = *(const bf16x8*)(ap1 + k * 32);
        acc0 = __builtin_amdgcn_mfma_f32_16x16x32_bf16(a0, bvv, acc0, 0, 0, 0);
        acc1 = __builtin_amdgcn_mfma_f32_16x16x32_bf16(a1, bvv, acc1, 0, 0, 0);
    }

    if (cls < NC) {
#pragma unroll
        for (int mf = 0; mf < 2; ++mf) {
            const f32x4 av = mf ? acc1 : acc0;
#pragma unroll
            for (int j = 0; j < 4; ++j) {
                const int m = mt * 32 + mf * 16 + kb * 4 + j;
                if (m < cnt) {
                    const int sid = sids[off + m];
                    part[((size_t)ks * 512 + sid) * NC + cls] = av[j];
                }
            }
        }
    }
}

// ---------------- fc reduce: sum 8 k-split partials, +bias, *pw; block 0 also computes aux loss ----------------
__global__ __launch_bounds__(256) void fc_reduce_kernel(
    const float* __restrict__ part,
    const float* __restrict__ fb,
    const int* __restrict__ sel,
    const float* __restrict__ pw,
    const float* __restrict__ probs,  // [512,4]
    float* __restrict__ outp,         // [512,100]
    float* __restrict__ aux_out)      // [1]
{
    const int tid = threadIdx.x;
    if (blockIdx.x == 0) {
        __shared__ float red[256][4];
        float4 pa = *(const float4*)(probs + tid * 4);
        float4 pb = *(const float4*)(probs + (tid + 256) * 4);
        red[tid][0] = pa.x + pb.x; red[tid][1] = pa.y + pb.y;
        red[tid][2] = pa.z + pb.z; red[tid][3] = pa.w + pb.w;
        __syncthreads();
        for (int off = 128; off > 0; off >>= 1) {
            if (tid < off) {
#pragma unroll
                for (int k = 0; k < 4; ++k) red[tid][k] += red[tid + off][k];
            }
            __syncthreads();
        }
        if (tid == 0) {
            float aux = 0.f;
#pragma unroll
            for (int k = 0; k < 4; ++k) {
                float mp = red[0][k] * (1.f / BATCH) - 0.25f;
                aux += mp * mp;
            }
            aux_out[0] = aux * 0.25f;
        }
    }

    const int i = blockIdx.x * 256 + tid;
    if (i >= BATCH * NC) return;
    const int s = i / NC, c = i - s * NC;
    float acc = 0.f;
#pragma unroll
    for (int k = 0; k < 8; ++k) acc += part[((size_t)k * 512 + s) * NC + c];
    outp[i] = pw[s] * (acc + fb[sel[s] * NC + c]);
}

extern "C" void kernel_launch(void* const* d_in, const int* in_sizes, int n_in,
                              void* d_out, int out_size, void* d_ws, size_t ws_size,
                              hipStream_t stream) {
    const float* x   = (const float*)d_in[0];
    const float* rcw = (const float*)d_in[1];
    const float* rcb = (const float*)d_in[2];
    const float* rfw = (const float*)d_in[3];
    const float* rfb = (const float*)d_in[4];
    const float* ew1 = (const float*)d_in[5];
    const float* eb1 = (const float*)d_in[6];
    const float* ew2 = (const float*)d_in[7];
    const float* eb2 = (const float*)d_in[8];
    const float* efw = (const float*)d_in[9];
    const float* efb = (const float*)d_in[10];
    (void)in_sizes; (void)n_in; (void)out_size; (void)ws_size;

    float* out       = (float*)d_out;
    float* final_out = out;            // [512,100]
    float* probs_out = out + 51200;    // [512,4]
    float* aux_out   = out + 53248;    // [1]

    char* ws = (char*)d_ws;
    int*    sel  = (int*)ws;                                  // 512 ints
    float*  pw   = (float*)(ws + 2048);                       // 512 f32
    uint*   h2b  = (uint*)(ws + 8192);                        // 4 MB
    ushort* fwb  = (ushort*)(ws + 8192 + 4194304);            // 3.28 MB
    ushort* w2t  = (ushort*)(ws + 8192 + 4194304 + 3276800);  // 144 KB
    ushort* w1t  = (ushort*)(ws + 8192 + 4194304 + 3276800 + 147456);           // 8 KB
    float*  part = (float*)(ws + 8192 + 4194304 + 3276800 + 147456 + 8192);     // 1.64 MB

    cvt_all_kernel<<<1904, 256, 0, stream>>>(efw, fwb, ew2, w2t, ew1, w1t);
    fused_expert_kernel<<<512, 512, 0, stream>>>(x, rcw, rcb, rfw, rfb, w1t, eb1,
                                                 w2t, eb2, probs_out, sel, pw, h2b);
    fc_mfma_kernel<<<dim3(16, 8, 4), 448, 0, stream>>>((const ushort*)h2b, fwb, sel, part);
    fc_reduce_kernel<<<200, 256, 0, stream>>>(part, efb, sel, pw, probs_out, final_out, aux_out);
}

// Round 19
// 40.481 us; speedup vs baseline: 1.0894x; 1.0894x over previous
//
#include <hip/hip_runtime.h>
#include <hip/hip_bf16.h>
#include <math.h>

#define BATCH 512
#define NC 100

typedef __attribute__((ext_vector_type(8))) short bf16x8;
typedef __attribute__((ext_vector_type(4))) float f32x4;

__device__ inline ushort f2bf(float f) {
    __hip_bfloat16 h = __float2bfloat16(f);
    return *reinterpret_cast<ushort*>(&h);
}

// ---------------- cvt: fc w f32->bf16 (0..1599), conv2 w transpose (1600..1887), conv1 im2col w (1888..1903) ----------------
__global__ __launch_bounds__(256) void cvt_all_kernel(const float* __restrict__ fw,
                                                      ushort* __restrict__ fwb,
                                                      const float* __restrict__ w2,
                                                      ushort* __restrict__ w2t,
                                                      const float* __restrict__ w1,
                                                      ushort* __restrict__ w1t)
{
    const int blk = blockIdx.x;
    if (blk < 1600) {
        const int i = (blk * 256 + threadIdx.x) * 4;   // 1,638,400 exact
        float4 v = *(const float4*)(fw + i);
        ushort o[4];
        o[0] = f2bf(v.x); o[1] = f2bf(v.y); o[2] = f2bf(v.z); o[3] = f2bf(v.w);
        *(uint2*)(fwb + i) = *(uint2*)o;
    } else if (blk < 1888) {
        const int i = (blk - 1600) * 256 + threadIdx.x;  // 73,728 exact
        const int ic = i & 31;
        const int oc = (i >> 5) & 63;
        const int et = i >> 11;
        const int e = et / 9, t = et % 9;
        w2t[i] = f2bf(w2[((e * 64 + oc) * 32 + ic) * 9 + t]);
    } else {
        // w1t[4][32oc][32k] bf16, k = ic*9+tap (27 real, 5 zero-pad)
        const int i = (blk - 1888) * 256 + threadIdx.x;  // 4096 exact
        const int row = i >> 5, k = i & 31;              // row = e*32+oc
        w1t[i] = (k < 27) ? f2bf(w1[row * 27 + k]) : (ushort)0;
    }
}

// ---------------- fused per-sample, 512 threads (8 waves): router(fp32) -> top1 -> conv1(MFMA) -> conv2(MFMA) ----------------
__global__ __launch_bounds__(512) void fused_expert_kernel(
    const float* __restrict__ x,       // [B,3,32,32]
    const float* __restrict__ rcw,     // [16,3,3,3]
    const float* __restrict__ rcb,     // [16]
    const float* __restrict__ rfw,     // [4,16]
    const float* __restrict__ rfb,     // [4]
    const ushort* __restrict__ w1t,    // [4][32][32] bf16 im2col conv1 weights (L2)
    const float* __restrict__ eb1,     // [4,32]
    const ushort* __restrict__ w2t,    // [4][9][64][32] bf16 (L2)
    const float* __restrict__ eb2,     // [4,64]
    float* __restrict__ probs_out,     // [512,4]
    int* __restrict__ sel,             // [512]
    float* __restrict__ pw,            // [512]
    uint* __restrict__ h2b)            // [B][2048] u32 (bf16 pairs): oc*64+py*8+px
{
    __shared__ float xs[3 * 34 * 40];                    // rows padded to 40 floats, 16.3 KB
    __shared__ float rcb_s[16];
    __shared__ float rfw_s[68];                          // [4][16] + 4 bias
    __shared__ float red[8][16];
    __shared__ float g_s[16];
    __shared__ int   sel_s;
    __shared__ float eb1_s[128];
    __shared__ __align__(16) ushort A_s[18 * 18 * 32];   // conv2 input, halo-padded, 20.7 KB

    const int b = blockIdx.x, tid = threadIdx.x;
    const int wvv = tid >> 6, lane = tid & 63;
    const int lr = lane & 15, kb = lane >> 4;

    // ---- phase 0: zero A_s halo + xs, stage small tables, then xs interior ----
    uint* A32 = (uint*)A_s;
    for (int i = tid; i < 1088; i += 512) {
        int y, xx, w;
        if (i < 576) { y = (i >= 288) ? 17 : 0; int r2 = i % 288; xx = r2 >> 4; w = r2 & 15; }
        else { int j = i - 576; y = 1 + (j >> 5); xx = ((j >> 4) & 1) ? 17 : 0; w = j & 15; }
        A32[(y * 18 + xx) * 16 + w] = 0u;
    }
    for (int i = tid; i < 3 * 34 * 40; i += 512) xs[i] = 0.f;
    if (tid < 128) eb1_s[tid] = eb1[tid];
    if (tid < 68) rfw_s[tid] = (tid < 64) ? rfw[tid] : rfb[tid - 64];
    if (tid >= 128 && tid < 144) rcb_s[tid - 128] = rcb[tid - 128];
    __syncthreads();
    const float* xb = x + b * 3072;
    for (int i = tid; i < 3072; i += 512) {
        int c = i >> 10, r = (i >> 5) & 31, cc = i & 31;
        xs[(c * 34 + r + 1) * 40 + (cc + 1)] = xb[i];
    }
    __syncthreads();

    // ---- phase 1: router conv+relu+mean fp32; thread = (oc 0..15) x (pg 0..15, half 0..1) ----
    {
        const int oc = tid & 15, sg = tid >> 4;      // sg 0..31
        const int pg = sg & 15, half = sg >> 4;
        const int c0 = half * 16;
        float w[27];
#pragma unroll
        for (int j = 0; j < 27; ++j) w[j] = rcw[oc * 27 + j];
        const float bias = rcb_s[oc];
        float a0[16], a1[16];
#pragma unroll
        for (int j = 0; j < 16; ++j) { a0[j] = 0.f; a1[j] = 0.f; }
#pragma unroll
        for (int c = 0; c < 3; ++c) {
#pragma unroll
            for (int ry = 0; ry < 4; ++ry) {
                const float* row = &xs[(c * 34 + 2 * pg + ry) * 40 + c0];
                float rv[18];
                float4 q0 = *(const float4*)(row);
                float4 q1 = *(const float4*)(row + 4);
                float4 q2 = *(const float4*)(row + 8);
                float4 q3 = *(const float4*)(row + 12);
                float2 q4 = *(const float2*)(row + 16);
                rv[0] = q0.x; rv[1] = q0.y; rv[2] = q0.z; rv[3] = q0.w;
                rv[4] = q1.x; rv[5] = q1.y; rv[6] = q1.z; rv[7] = q1.w;
                rv[8] = q2.x; rv[9] = q2.y; rv[10] = q2.z; rv[11] = q2.w;
                rv[12] = q3.x; rv[13] = q3.y; rv[14] = q3.z; rv[15] = q3.w;
                rv[16] = q4.x; rv[17] = q4.y;
                if (ry < 3) {
#pragma unroll
                    for (int kx = 0; kx < 3; ++kx) {
                        const float wv = w[c * 9 + ry * 3 + kx];
#pragma unroll
                        for (int j = 0; j < 16; ++j) a0[j] += wv * rv[j + kx];
                    }
                }
                if (ry > 0) {
#pragma unroll
                    for (int kx = 0; kx < 3; ++kx) {
                        const float wv = w[c * 9 + (ry - 1) * 3 + kx];
#pragma unroll
                        for (int j = 0; j < 16; ++j) a1[j] += wv * rv[j + kx];
                    }
                }
            }
        }
        float accm = 0.f;
#pragma unroll
        for (int j = 0; j < 16; ++j)
            accm += fmaxf(a0[j] + bias, 0.f) + fmaxf(a1[j] + bias, 0.f);
        // wave holds 4 sg x 16 oc: lane = ((sg&3)<<4)|oc
        accm += __shfl_down(accm, 32);
        accm += __shfl_down(accm, 16);
        if (lane < 16) red[wvv][lane] = accm;   // lane<16 -> oc = lane
    }
    __syncthreads();
    if (tid < 16) {
        float s = 0.f;
#pragma unroll
        for (int w = 0; w < 8; ++w) s += red[w][tid];
        g_s[tid] = s * (1.f / 1024.f);
    }
    __syncthreads();

    // ---- phase 2: fc(16->4) + softmax + top1 (thread 0, all-LDS) ----
    if (tid == 0) {
        float logits[4];
#pragma unroll
        for (int e = 0; e < 4; ++e) {
            float s = rfw_s[64 + e];
#pragma unroll
            for (int o = 0; o < 16; ++o) s += g_s[o] * rfw_s[e * 16 + o];
            logits[e] = s;
        }
        float m = fmaxf(fmaxf(logits[0], logits[1]), fmaxf(logits[2], logits[3]));
        float ex[4], ssum = 0.f;
#pragma unroll
        for (int e = 0; e < 4; ++e) { ex[e] = __expf(logits[e] - m); ssum += ex[e]; }
        const float inv = 1.f / ssum;
        float p[4];
#pragma unroll
        for (int e = 0; e < 4; ++e) p[e] = ex[e] * inv;
        int am = 0; float best = p[0];
#pragma unroll
        for (int e = 1; e < 4; ++e) { if (p[e] > best) { best = p[e]; am = e; } }
        *(float4*)(probs_out + b * 4) = make_float4(p[0], p[1], p[2], p[3]);
        sel[b] = am;
        pw[b] = best;
        sel_s = am;
    }
    __syncthreads();
    const int e = sel_s;

    // ---- phase 4: conv1 via im2col MFMA; 8 waves x 8 mf (M=1024 corner-major, N=32, K=32) ----
    {
        const ushort* bsrc = w1t + (e * 32 + lr) * 32 + kb * 8;   // L2-hot 8 KB table
        const bf16x8 b0 = *(const bf16x8*)(bsrc);
        const bf16x8 b1 = *(const bf16x8*)(bsrc + 16 * 32);
        const float bv0 = eb1_s[e * 32 + lr];
        const float bv1 = eb1_s[e * 32 + 16 + lr];

        int offj[8], valj[8];
#pragma unroll
        for (int jj = 0; jj < 8; ++jj) {
            int k = kb * 8 + jj;
            int ic = (k * 57) >> 9; ic = ic > 2 ? 2 : ic;
            int tap = k - ic * 9; tap = tap > 8 ? 8 : tap;
            int ky = (tap * 11) >> 5;
            int kx = tap - ky * 3;
            offj[jj] = (ic * 34 + ky) * 40 + kx;
            valj[jj] = (k < 27);
        }

#pragma unroll 2
        for (int mf = 0; mf < 8; ++mf) {
            const int pA = wvv * 32 + mf * 4 + (lr >> 2);  // pooled pixel of this im2col row
            const int c2 = lr & 3;                         // corner
            const int yA = ((pA >> 4) << 1) + (c2 >> 1);
            const int xA = ((pA & 15) << 1) + (c2 & 1);
            const int base = yA * 40 + xA;
            union { uint u[4]; bf16x8 v; } U;
#pragma unroll
            for (int jp = 0; jp < 4; ++jp) {
                float v0 = valj[2 * jp]     ? xs[base + offj[2 * jp]]     : 0.f;
                float v1 = valj[2 * jp + 1] ? xs[base + offj[2 * jp + 1]] : 0.f;
                U.u[jp] = (uint)f2bf(v0) | ((uint)f2bf(v1) << 16);
            }
            const f32x4 z = {0.f, 0.f, 0.f, 0.f};
            f32x4 c0 = __builtin_amdgcn_mfma_f32_16x16x32_bf16(U.v, b0, z, 0, 0, 0);
            f32x4 c1 = __builtin_amdgcn_mfma_f32_16x16x32_bf16(U.v, b1, z, 0, 0, 0);
            const int pp = wvv * 32 + mf * 4 + kb;
            const int py = pp >> 4, px = pp & 15;
            ushort* dst = A_s + ((py + 1) * 18 + (px + 1)) * 32 + lr;
            float m0 = fmaxf(fmaxf(c0[0], c0[1]), fmaxf(c0[2], c0[3]));
            float m1 = fmaxf(fmaxf(c1[0], c1[1]), fmaxf(c1[2], c1[3]));
            dst[0]  = f2bf(fmaxf(m0 + bv0, 0.f));
            dst[16] = f2bf(fmaxf(m1 + bv1, 0.f));
        }
    }
    __syncthreads();

    // ---- phase 5: conv2 via 9 tap-MFMAs; 8 waves = (wy 0..3) x (wn 0..1), acc[4][2] ----
    {
        const int wy = wvv & 3, wn = wvv >> 2;
        const ushort* wgl = w2t + (size_t)e * 18432 + lr * 32 + kb * 8;

        f32x4 acc[4][2];
#pragma unroll
        for (int m = 0; m < 4; ++m)
#pragma unroll
            for (int n = 0; n < 2; ++n)
                acc[m][n] = (f32x4){0.f, 0.f, 0.f, 0.f};

#pragma unroll
        for (int t = 0; t < 9; ++t) {
            const int ky = t / 3, kx = t % 3;
            bf16x8 af[4], bfr[2];
#pragma unroll
            for (int m = 0; m < 4; ++m) {
                const int y = wy * 4 + m;
                af[m] = *(const bf16x8*)(A_s + ((y + ky) * 18 + (lr + kx)) * 32 + kb * 8);
            }
#pragma unroll
            for (int n = 0; n < 2; ++n)
                bfr[n] = *(const bf16x8*)(wgl + (t * 64 + (wn * 2 + n) * 16) * 32);
#pragma unroll
            for (int m = 0; m < 4; ++m)
#pragma unroll
                for (int n = 0; n < 2; ++n)
                    acc[m][n] = __builtin_amdgcn_mfma_f32_16x16x32_bf16(af[m], bfr[n], acc[m][n], 0, 0, 0);
        }

#pragma unroll
        for (int q = 0; q < 2; ++q) {
            const int py = wy * 2 + q;
#pragma unroll
            for (int n = 0; n < 2; ++n) {
                const int oc = (wn * 2 + n) * 16 + lr;
                const float bn = eb2[e * 64 + oc];
                const f32x4 ca = acc[2 * q][n];
                const f32x4 cb = acc[2 * q + 1][n];
                float p0 = fmaxf(fmaxf(ca[0], ca[1]), fmaxf(cb[0], cb[1]));
                float p1 = fmaxf(fmaxf(ca[2], ca[3]), fmaxf(cb[2], cb[3]));
                float r0 = fmaxf(p0 + bn, 0.f);
                float r1 = fmaxf(p1 + bn, 0.f);
                uint pk = (uint)f2bf(r0) | ((uint)f2bf(r1) << 16);
                h2b[(size_t)b * 2048 + oc * 32 + py * 4 + kb] = pk;
            }
        }
    }
}

// ---------------- fc: per-block ballot grouping + K-split MFMA, partials to part[8][512][100] ----------------
// Grouping recomputed per block (~0.1us): waves 0..6 rank chunks 0..6, wave 0 also chunk 7.
// Identical deterministic ordering to the old scan kernel (chunk-major, lane rank).
__global__ __launch_bounds__(448) void fc_mfma_kernel(
    const ushort* __restrict__ h2b,   // [512,4096] bf16
    const ushort* __restrict__ fwb,   // [4,100,4096] bf16
    const int* __restrict__ sel,      // [512]
    float* __restrict__ part)         // [8][512][100] f32
{
    __shared__ int wcnt[4][8];
    __shared__ int wbase[4][8];
    __shared__ int soff[5];
    __shared__ int sids[512];

    const int mt = blockIdx.x, ks = blockIdx.y, e = blockIdx.z;
    const int tid = threadIdx.x;
    const int wv = tid >> 6, lane = tid & 63;

    // ---- grouping preamble ----
    const int s0 = wv * 64 + lane;          // 0..447
    const int e0 = sel[s0];
    unsigned long long m0[4];
#pragma unroll
    for (int k = 0; k < 4; ++k) m0[k] = __ballot(e0 == k);
    if (lane == 0) {
#pragma unroll
        for (int k = 0; k < 4; ++k) wcnt[k][wv] = __popcll(m0[k]);
    }
    int e1 = 0;
    unsigned long long m1[4] = {0, 0, 0, 0};
    if (wv == 0) {
        const int s1 = 448 + lane;
        e1 = sel[s1];
#pragma unroll
        for (int k = 0; k < 4; ++k) m1[k] = __ballot(e1 == k);
        if (lane == 0) {
#pragma unroll
            for (int k = 0; k < 4; ++k) wcnt[k][7] = __popcll(m1[k]);
        }
    }
    __syncthreads();
    if (tid == 0) {
        int o = 0;
        for (int k = 0; k < 4; ++k) {
            soff[k] = o;
            for (int w = 0; w < 8; ++w) { wbase[k][w] = o; o += wcnt[k][w]; }
        }
        soff[4] = o;
    }
    __syncthreads();
    const unsigned long long below = (lane == 0) ? 0ull : (~0ull >> (64 - lane));
    {
        const int r = __popcll(m0[e0] & below);
        sids[wbase[e0][wv] + r] = s0;
    }
    if (wv == 0) {
        const int r = __popcll(m1[e1] & below);
        sids[wbase[e1][7] + r] = 448 + lane;
    }
    __syncthreads();

    const int off = soff[e], cnt = soff[e + 1] - off;
    if (mt * 16 >= cnt) return;

    // ---- MFMA K-split GEMM ----
    const int lr = lane & 15, kb = lane >> 4;
    const int cls = wv * 16 + lr;
    const int clsc = cls < NC ? cls : NC - 1;
    const int slot = mt * 16 + lr;
    const int sidx = sids[off + (slot < cnt ? slot : cnt - 1)];

    const ushort* ap = h2b + (size_t)sidx * 4096 + ks * 512 + kb * 8;
    const ushort* bp = fwb + (size_t)(e * NC + clsc) * 4096 + ks * 512 + kb * 8;

    f32x4 acc = {0.f, 0.f, 0.f, 0.f};
#pragma unroll
    for (int k = 0; k < 16; ++k) {
        bf16x8 a = *(const bf16x8*)(ap + k * 32);
        bf16x8 b = *(const bf16x8*)(bp + k * 32);
        acc = __builtin_amdgcn_mfma_f32_16x16x32_bf16(a, b, acc, 0, 0, 0);
    }

    if (cls < NC) {
#pragma unroll
        for (int j = 0; j < 4; ++j) {
            const int m = mt * 16 + kb * 4 + j;
            if (m < cnt) {
                const int sid = sids[off + m];
                part[((size_t)ks * 512 + sid) * NC + cls] = acc[j];
            }
        }
    }
}

// ---------------- fc reduce: sum 8 k-split partials, +bias, *pw; block 0 also computes aux loss ----------------
__global__ __launch_bounds__(256) void fc_reduce_kernel(
    const float* __restrict__ part,
    const float* __restrict__ fb,
    const int* __restrict__ sel,
    const float* __restrict__ pw,
    const float* __restrict__ probs,  // [512,4]
    float* __restrict__ outp,         // [512,100]
    float* __restrict__ aux_out)      // [1]
{
    const int tid = threadIdx.x;
    if (blockIdx.x == 0) {
        __shared__ float red[256][4];
        float4 pa = *(const float4*)(probs + tid * 4);
        float4 pb = *(const float4*)(probs + (tid + 256) * 4);
        red[tid][0] = pa.x + pb.x; red[tid][1] = pa.y + pb.y;
        red[tid][2] = pa.z + pb.z; red[tid][3] = pa.w + pb.w;
        __syncthreads();
        for (int off = 128; off > 0; off >>= 1) {
            if (tid < off) {
#pragma unroll
                for (int k = 0; k < 4; ++k) red[tid][k] += red[tid + off][k];
            }
            __syncthreads();
        }
        if (tid == 0) {
            float aux = 0.f;
#pragma unroll
            for (int k = 0; k < 4; ++k) {
                float mp = red[0][k] * (1.f / BATCH) - 0.25f;
                aux += mp * mp;
            }
            aux_out[0] = aux * 0.25f;
        }
    }

    const int i = blockIdx.x * 256 + tid;
    if (i >= BATCH * NC) return;
    const int s = i / NC, c = i - s * NC;
    float acc = 0.f;
#pragma unroll
    for (int k = 0; k < 8; ++k) acc += part[((size_t)k * 512 + s) * NC + c];
    outp[i] = pw[s] * (acc + fb[sel[s] * NC + c]);
}

extern "C" void kernel_launch(void* const* d_in, const int* in_sizes, int n_in,
                              void* d_out, int out_size, void* d_ws, size_t ws_size,
                              hipStream_t stream) {
    const float* x   = (const float*)d_in[0];
    const float* rcw = (const float*)d_in[1];
    const float* rcb = (const float*)d_in[2];
    const float* rfw = (const float*)d_in[3];
    const float* rfb = (const float*)d_in[4];
    const float* ew1 = (const float*)d_in[5];
    const float* eb1 = (const float*)d_in[6];
    const float* ew2 = (const float*)d_in[7];
    const float* eb2 = (const float*)d_in[8];
    const float* efw = (const float*)d_in[9];
    const float* efb = (const float*)d_in[10];
    (void)in_sizes; (void)n_in; (void)out_size; (void)ws_size;

    float* out       = (float*)d_out;
    float* final_out = out;            // [512,100]
    float* probs_out = out + 51200;    // [512,4]
    float* aux_out   = out + 53248;    // [1]

    char* ws = (char*)d_ws;
    int*    sel  = (int*)ws;                                  // 512 ints
    float*  pw   = (float*)(ws + 2048);                       // 512 f32
    uint*   h2b  = (uint*)(ws + 8192);                        // 4 MB
    ushort* fwb  = (ushort*)(ws + 8192 + 4194304);            // 3.28 MB
    ushort* w2t  = (ushort*)(ws + 8192 + 4194304 + 3276800);  // 144 KB
    ushort* w1t  = (ushort*)(ws + 8192 + 4194304 + 3276800 + 147456);           // 8 KB
    float*  part = (float*)(ws + 8192 + 4194304 + 3276800 + 147456 + 8192);     // 1.64 MB

    cvt_all_kernel<<<1904, 256, 0, stream>>>(efw, fwb, ew2, w2t, ew1, w1t);
    fused_expert_kernel<<<512, 512, 0, stream>>>(x, rcw, rcb, rfw, rfb, w1t, eb1,
                                                 w2t, eb2, probs_out, sel, pw, h2b);
    fc_mfma_kernel<<<dim3(32, 8, 4), 448, 0, stream>>>((const ushort*)h2b, fwb, sel, part);
    fc_reduce_kernel<<<200, 256, 0, stream>>>(part, efb, sel, pw, probs_out, final_out, aux_out);
}